// Round 1
// 2557.739 us; speedup vs baseline: 1.3046x; 1.3046x over previous
//
#include <hip/hip_runtime.h>
#include <math.h>

// Problem dims (fixed by reference): B=256, T=1000, D=700, H=200, O=35
// M = B*T = 256000, K = D = 700, N = H = 200
//
// Pipeline:
//   1) gemm_in : i_all[m,n] = x[m,:] . W_in[n,:] + b_in[n]   (fp32, VALU-bound)
//   2) lif_scan: per (b,h) leaky-integrate-fire over t, spike counts
//   3) out_gemm: out[b,o] = counts[b,:] . W_out[o,:] + b_out[o]
//
// v2 changes vs v1 (theory: latency-bound, both pipes idle):
//   - __launch_bounds__(320,3): v1's default capped VGPR at 64 with 64 live
//     accumulators -> scheduler serialized the inner loop. Allow ~170.
//   - Double-buffered LDS + register prefetch: global loads for tile k+1
//     issue before compute of tile k; one barrier per k-tile instead of two
//     with a full vmcnt drain.
//   - XCD-aware block remap: the 5 n-tiles sharing an x m-tile get the same
//     id%8 and adjacent dispatch slots -> x comes from that XCD's L2 instead
//     of 5x from HBM (FETCH was 1.88 GB vs 717 MB ideal).
//   - lif_scan: 2-deep software pipeline (prefetch chunk c+1 into regs while
//     computing chunk c); 0.78 waves/SIMD means there is no TLP, so latency
//     must be hidden by ILP inside each thread.
// Numerics are bitwise-identical to v1: same per-thread summation order,
// same 20-k chunk accumulator, same __fmul_rn/__fadd_rn scan sequence.

#define TILE_M 256
#define TILE_N 40
#define TILE_K 20
#define GEMM_THREADS 320  // 5 waves; each wave owns an 8-wide n-strip
#define NTILES 35         // 700 / TILE_K

__global__ __launch_bounds__(GEMM_THREADS, 3) void gemm_in(
    const float* __restrict__ x, const float* __restrict__ W,
    const float* __restrict__ b_in, float* __restrict__ i_all) {
  // LDS layouts: As[k][m] (m-contiguous), Ws[k][n] (n-contiguous), x2 buffers
  __shared__ __align__(16) float As[2 * TILE_K * TILE_M];
  __shared__ __align__(16) float Ws[2 * TILE_K * TILE_N];

  const int tid = threadIdx.x;
  const int wave = tid >> 6;   // 0..4 -> n-strip
  const int lane = tid & 63;   // rows 4*lane..4*lane+3

  // XCD-aware remap of the 1D block id (5000 blocks = 1000 m-tiles x 5
  // n-tiles). Dispatch round-robins id%8 across XCDs; we arrange the 5
  // n-tiles of one m-tile to share id%8 and be 8 apart (same round):
  //   id = xcd + 8*(5*gq + j),  m-tile g = xcd + 8*gq,  n-tile = j
  // Bijective for g in [0,1000), j in [0,5).
  const int id = blockIdx.x;
  const int xcd = id & 7;
  const int k5 = id >> 3;       // 0..624
  const int ntile = k5 % 5;
  const int gq = k5 / 5;        // 0..124
  const int mtile = xcd + 8 * gq;

  const long m0 = (long)mtile * TILE_M;
  const int n0 = ntile * TILE_N;

  // Per-thread staging addresses (A: 4 float4 per thread, j = c*320+tid,
  // row = j&255 -> conflict-free LDS writes, kq = j>>8 in 0..4)
  const float* aptr0;
  const float* aptr1;
  const float* aptr2;
  const float* aptr3;
  {
    const int j0 = 0 * GEMM_THREADS + tid;
    const int j1 = 1 * GEMM_THREADS + tid;
    const int j2 = 2 * GEMM_THREADS + tid;
    const int j3 = 3 * GEMM_THREADS + tid;
    aptr0 = x + (m0 + (j0 & 255)) * 700 + (j0 >> 8) * 4;
    aptr1 = x + (m0 + (j1 & 255)) * 700 + (j1 >> 8) * 4;
    aptr2 = x + (m0 + (j2 & 255)) * 700 + (j2 >> 8) * 4;
    aptr3 = x + (m0 + (j3 & 255)) * 700 + (j3 >> 8) * 4;
  }
  const float* wptr = nullptr;
  int wrow = 0, wkq = 0;
  if (tid < 200) {
    wrow = tid % 40;
    wkq = tid / 40;
    wptr = W + (long)(n0 + wrow) * 700 + wkq * 4;
  }

  float acc[4][8];
#pragma unroll
  for (int mi = 0; mi < 4; ++mi)
#pragma unroll
    for (int ni = 0; ni < 8; ++ni) acc[mi][ni] = 0.0f;

  // ---- prologue: stage tile 0 into buffer 0 ----
  {
    float4 av0 = *(const float4*)(aptr0);
    float4 av1 = *(const float4*)(aptr1);
    float4 av2 = *(const float4*)(aptr2);
    float4 av3 = *(const float4*)(aptr3);
    float4 wv4 = make_float4(0.f, 0.f, 0.f, 0.f);
    if (tid < 200) wv4 = *(const float4*)(wptr);

    const float4 avs[4] = {av0, av1, av2, av3};
#pragma unroll
    for (int c = 0; c < 4; ++c) {
      const int j = c * GEMM_THREADS + tid;
      const int row = j & 255;
      const int kq = j >> 8;
      As[(kq * 4 + 0) * TILE_M + row] = avs[c].x;
      As[(kq * 4 + 1) * TILE_M + row] = avs[c].y;
      As[(kq * 4 + 2) * TILE_M + row] = avs[c].z;
      As[(kq * 4 + 3) * TILE_M + row] = avs[c].w;
    }
    if (tid < 200) {
      Ws[(wkq * 4 + 0) * TILE_N + wrow] = wv4.x;
      Ws[(wkq * 4 + 1) * TILE_N + wrow] = wv4.y;
      Ws[(wkq * 4 + 2) * TILE_N + wrow] = wv4.z;
      Ws[(wkq * 4 + 3) * TILE_N + wrow] = wv4.w;
    }
  }
  __syncthreads();

  int cur = 0;
  for (int it = 0; it < NTILES; ++it) {
    // Issue next tile's global loads now; they stay in flight (vmcnt) under
    // the 640-FMA compute phase and only drain at the LDS write below.
    float4 av0, av1, av2, av3, wv4;
    const bool more = (it + 1 < NTILES);
    if (more) {
      const int kt = (it + 1) * TILE_K;
      av0 = *(const float4*)(aptr0 + kt);
      av1 = *(const float4*)(aptr1 + kt);
      av2 = *(const float4*)(aptr2 + kt);
      av3 = *(const float4*)(aptr3 + kt);
      if (tid < 200) wv4 = *(const float4*)(wptr + kt);
    }

    // Per-tile chunk accumulator (reduces fp32 summation error ~3x;
    // preserves v1's exact summation order -> absmax 0.0)
    float at[4][8];
#pragma unroll
    for (int mi = 0; mi < 4; ++mi)
#pragma unroll
      for (int ni = 0; ni < 8; ++ni) at[mi][ni] = 0.0f;

    const float* Ab = As + cur * (TILE_K * TILE_M);
    const float* Wb = Ws + cur * (TILE_K * TILE_N);
#pragma unroll 4
    for (int kk = 0; kk < TILE_K; ++kk) {
      const float4 a = *(const float4*)(Ab + kk * TILE_M + lane * 4);
      const float4 w0 = *(const float4*)(Wb + kk * TILE_N + wave * 8);
      const float4 w1 = *(const float4*)(Wb + kk * TILE_N + wave * 8 + 4);
      const float avx[4] = {a.x, a.y, a.z, a.w};
      const float wvx[8] = {w0.x, w0.y, w0.z, w0.w, w1.x, w1.y, w1.z, w1.w};
#pragma unroll
      for (int mi = 0; mi < 4; ++mi)
#pragma unroll
        for (int ni = 0; ni < 8; ++ni) at[mi][ni] += avx[mi] * wvx[ni];
    }
#pragma unroll
    for (int mi = 0; mi < 4; ++mi)
#pragma unroll
      for (int ni = 0; ni < 8; ++ni) acc[mi][ni] += at[mi][ni];

    if (more) {
      // Write prefetched regs into the other buffer. Safe with ONE barrier:
      // buf cur^1 was last read in iter it-1, and every wave passed the
      // barrier at the end of iter it-1 after those reads.
      float* Aw = As + (cur ^ 1) * (TILE_K * TILE_M);
      float* Ww = Ws + (cur ^ 1) * (TILE_K * TILE_N);
      const float4 avs[4] = {av0, av1, av2, av3};
#pragma unroll
      for (int c = 0; c < 4; ++c) {
        const int j = c * GEMM_THREADS + tid;
        const int row = j & 255;
        const int kq = j >> 8;
        Aw[(kq * 4 + 0) * TILE_M + row] = avs[c].x;
        Aw[(kq * 4 + 1) * TILE_M + row] = avs[c].y;
        Aw[(kq * 4 + 2) * TILE_M + row] = avs[c].z;
        Aw[(kq * 4 + 3) * TILE_M + row] = avs[c].w;
      }
      if (tid < 200) {
        Ww[(wkq * 4 + 0) * TILE_N + wrow] = wv4.x;
        Ww[(wkq * 4 + 1) * TILE_N + wrow] = wv4.y;
        Ww[(wkq * 4 + 2) * TILE_N + wrow] = wv4.z;
        Ww[(wkq * 4 + 3) * TILE_N + wrow] = wv4.w;
      }
      __syncthreads();
      cur ^= 1;
    }
  }

  // Epilogue: add bias, store 2 float4 per row
  float bv[8];
#pragma unroll
  for (int ni = 0; ni < 8; ++ni) bv[ni] = b_in[n0 + wave * 8 + ni];
#pragma unroll
  for (int mi = 0; mi < 4; ++mi) {
    const long m = m0 + lane * 4 + mi;
    float4 o0, o1;
    o0.x = acc[mi][0] + bv[0];
    o0.y = acc[mi][1] + bv[1];
    o0.z = acc[mi][2] + bv[2];
    o0.w = acc[mi][3] + bv[3];
    o1.x = acc[mi][4] + bv[4];
    o1.y = acc[mi][5] + bv[5];
    o1.z = acc[mi][6] + bv[6];
    o1.w = acc[mi][7] + bv[7];
    *(float4*)(i_all + m * 200 + n0 + wave * 8) = o0;
    *(float4*)(i_all + m * 200 + n0 + wave * 8 + 4) = o1;
  }
}

// One thread per (b,h). 200 blocks x 256 threads = 51200 exactly.
// Only 0.78 waves/SIMD -> no TLP; hide load latency with a 2-deep
// register pipeline (prefetch chunk c+1 while stepping through chunk c).
__global__ __launch_bounds__(256) void lif_scan(
    const float* __restrict__ i_all, const float* __restrict__ tau_p,
    float* __restrict__ counts) {
  const int idx = blockIdx.x * 256 + threadIdx.x;
  const int b = idx / 200;
  const int h = idx - b * 200;
  const float tau = tau_p[0];
  // Mirror numpy float32: sigmoid via expf, no fused ops in the scan
  const float alpha = 1.0f / (1.0f + expf(-tau));
  const float om = 1.0f - alpha;
  const float* p = i_all + (long)b * 200000 + h;
  float v = 0.0f;
  float cnt = 0.0f;

  float bufA[20], bufB[20];
#pragma unroll
  for (int j = 0; j < 20; ++j) bufA[j] = p[(long)j * 200];

  for (int t0 = 0; t0 < 1000; t0 += 40) {
    // issue loads for chunk at t0+20 (in flight during bufA compute)
    if (t0 + 20 < 1000) {
#pragma unroll
      for (int j = 0; j < 20; ++j) bufB[j] = p[(long)(t0 + 20 + j) * 200];
    }
#pragma unroll
    for (int j = 0; j < 20; ++j) {
      // v = alpha*v + (1-alpha)*i  -- exact np rounding (no FMA contraction)
      const float v1 = __fadd_rn(__fmul_rn(alpha, v), __fmul_rn(om, bufA[j]));
      const float s = (v1 >= 1.0f) ? 1.0f : 0.0f;
      v = v1 - s;
      cnt += s;
    }
    // issue loads for chunk at t0+40 (in flight during bufB compute)
    if (t0 + 40 < 1000) {
#pragma unroll
      for (int j = 0; j < 20; ++j) bufA[j] = p[(long)(t0 + 40 + j) * 200];
    }
#pragma unroll
    for (int j = 0; j < 20; ++j) {
      const float v1 = __fadd_rn(__fmul_rn(alpha, v), __fmul_rn(om, bufB[j]));
      const float s = (v1 >= 1.0f) ? 1.0f : 0.0f;
      v = v1 - s;
      cnt += s;
    }
  }
  counts[idx] = cnt;
}

__global__ __launch_bounds__(64) void out_gemm(
    const float* __restrict__ counts, const float* __restrict__ W_out,
    const float* __restrict__ b_out, float* __restrict__ out) {
  const int b = blockIdx.x;
  const int o = threadIdx.x;
  if (o >= 35) return;
  const float* c = counts + b * 200;
  const float* w = W_out + o * 200;
  float s = 0.0f;
#pragma unroll 8
  for (int h = 0; h < 200; ++h) s += c[h] * w[h];
  out[b * 35 + o] = s + b_out[o];
}

extern "C" void kernel_launch(void* const* d_in, const int* in_sizes, int n_in,
                              void* d_out, int out_size, void* d_ws,
                              size_t ws_size, hipStream_t stream) {
  const float* x = (const float*)d_in[0];      // (256,1000,700)
  const float* W_in = (const float*)d_in[1];   // (200,700)
  const float* b_in = (const float*)d_in[2];   // (200,)
  const float* W_out = (const float*)d_in[3];  // (35,200)
  const float* b_out = (const float*)d_in[4];  // (35,)
  const float* tau = (const float*)d_in[5];    // scalar
  float* out = (float*)d_out;                  // (256,35) fp32

  float* i_all = (float*)d_ws;  // 256000*200 floats = 204.8 MB
  float* counts = (float*)((char*)d_ws + (size_t)256000 * 200 * sizeof(float));

  gemm_in<<<dim3(5000), dim3(GEMM_THREADS), 0, stream>>>(x, W_in, b_in, i_all);
  lif_scan<<<200, 256, 0, stream>>>(i_all, tau, counts);
  out_gemm<<<256, 64, 0, stream>>>(counts, W_out, b_out, out);
}